// Round 7
// baseline (88.399 us; speedup 1.0000x reference)
//
#include <hip/hip_runtime.h>
#include <hip/hip_fp16.h>

// DeepseekV4HashRouter: B=4,S=4096,D=2048,E=256,K=8,V=128000
#define DIM    2048
#define NEXP   256
#define TOPK   8
#define RSCALE 2.5f
#define BM     64
#define BK     64
#define NT     (DIM / BK)   // 32 K-steps

typedef _Float16 h8 __attribute__((ext_vector_type(8)));
typedef float f32x4 __attribute__((ext_vector_type(4)));

__device__ __forceinline__ unsigned int pkh(float x, float y) {
    // v_cvt_pkrtz_f16_f32: lo=x, hi=y
    return __builtin_bit_cast(unsigned int, __builtin_amdgcn_cvt_pkrtz(x, y));
}

__global__ __launch_bounds__(256) void convert_weight_f16(
    const float* __restrict__ w, unsigned int* __restrict__ wh, int n4) {
    int i = blockIdx.x * blockDim.x + threadIdx.x;  // over float4s
    if (i < n4) {
        float4 f = reinterpret_cast<const float4*>(w)[i];
        uint2 o;
        o.x = pkh(f.x, f.y);
        o.y = pkh(f.z, f.w);
        reinterpret_cast<uint2*>(wh)[i] = o;
    }
}

// Dense MFMA router: block = 64 tokens x 256 experts, K = 2048.
// Grid = M/64 = 256 blocks = 1 per CU.
__global__ __launch_bounds__(256) void router_mfma(
    const float* __restrict__ hidden,   // [M, D] fp32
    const int* __restrict__ token_ids,  // [M] int32
    const ushort* __restrict__ wh,      // [E, D] f16
    const int* __restrict__ tid2eid,    // [V, K] int32
    float* __restrict__ out,            // probs [M,E] then map [M,E]
    int M) {
    __shared__ alignas(16) ushort aLds[2][BM * BK];    // 2 x 8KB
    __shared__ alignas(16) ushort bLds[2][NEXP * BK];  // 2 x 32KB
    __shared__ float cLds[BM][NEXP + 1];               // 64.25KB (padded)

    const int t  = threadIdx.x;
    const int w  = t >> 6;        // wave 0..3 -> expert strip w*64
    const int l  = t & 63;
    const int n0 = blockIdx.x * BM;

    // --- A staging geometry: thread t -> token row ar, k-quarter aq (16 f32)
    const int ar = t >> 2;
    const int aq = t & 3;
    const int as0 = (aq * 2)     ^ (ar & 7);  // swizzled 16B-block slots
    const int as1 = (aq * 2 + 1) ^ (ar & 7);

    // --- B staging: per wave 8 issues of 1KB (8 expert rows each),
    // linear LDS dest (global_load_lds), swizzle applied on global source.
    auto stageB = [&](int kt, int s) {
#pragma unroll
        for (int i = 0; i < 8; ++i) {
            const int e0 = (w * 8 + i) * 8;
            const int e  = e0 + (l >> 3);
            const int gb = (l & 7) ^ (e & 7);
            const ushort* g = wh + (size_t)e * DIM + kt * BK + gb * 8;
            const ushort* lp = &bLds[s][e0 * BK];
            __builtin_amdgcn_global_load_lds(
                (const unsigned int __attribute__((address_space(1)))*)g,
                (unsigned int __attribute__((address_space(3)))*)lp, 16, 0, 0);
        }
    };
    auto writeA = [&](int s, const float4* fa) {
        uint4 u0, u1;
        u0.x = pkh(fa[0].x, fa[0].y); u0.y = pkh(fa[0].z, fa[0].w);
        u0.z = pkh(fa[1].x, fa[1].y); u0.w = pkh(fa[1].z, fa[1].w);
        u1.x = pkh(fa[2].x, fa[2].y); u1.y = pkh(fa[2].z, fa[2].w);
        u1.z = pkh(fa[3].x, fa[3].y); u1.w = pkh(fa[3].z, fa[3].w);
        *reinterpret_cast<uint4*>(&aLds[s][ar * BK + as0 * 8]) = u0;
        *reinterpret_cast<uint4*>(&aLds[s][ar * BK + as1 * 8]) = u1;
    };

    // Prologue: stage kt=0 into buffer 0.
    {
        const float4* ap = reinterpret_cast<const float4*>(
            hidden + (size_t)(n0 + ar) * DIM + aq * 16);
        float4 fa[4] = {ap[0], ap[1], ap[2], ap[3]};
        stageB(0, 0);
        writeA(0, fa);
    }
    __syncthreads();

    f32x4 acc[4][4] = {};
    const int row16 = l & 15;
    const int quad  = l >> 4;

    for (int kt = 0; kt < NT; ++kt) {
        const int cur = kt & 1;
        const bool more = (kt + 1) < NT;
        float4 fa[4];
        if (more) {  // issue next-tile loads before compute (T14 split)
            const float4* ap = reinterpret_cast<const float4*>(
                hidden + (size_t)(n0 + ar) * DIM + (kt + 1) * BK + aq * 16);
            fa[0] = ap[0]; fa[1] = ap[1]; fa[2] = ap[2]; fa[3] = ap[3];
            stageB(kt + 1, cur ^ 1);
        }
        // Compute on buffer cur: 2 k32-steps x 16 MFMA.
#pragma unroll
        for (int kk = 0; kk < 2; ++kk) {
            const int bb = kk * 4 + quad;
            h8 af[4], bf[4];
#pragma unroll
            for (int mi = 0; mi < 4; ++mi) {
                const int r = mi * 16 + row16;
                af[mi] = *reinterpret_cast<const h8*>(
                    &aLds[cur][r * BK + (bb ^ (r & 7)) * 8]);
            }
#pragma unroll
            for (int ni = 0; ni < 4; ++ni) {
                const int c = w * 64 + ni * 16 + row16;
                bf[ni] = *reinterpret_cast<const h8*>(
                    &bLds[cur][c * BK + (bb ^ (c & 7)) * 8]);
            }
#pragma unroll
            for (int mi = 0; mi < 4; ++mi)
#pragma unroll
                for (int ni = 0; ni < 4; ++ni)
                    acc[mi][ni] = __builtin_amdgcn_mfma_f32_16x16x32_f16(
                        af[mi], bf[ni], acc[mi][ni], 0, 0, 0);
        }
        if (more) writeA(cur ^ 1, fa);
        __syncthreads();
    }

    // Scatter logits to padded C-LDS. D lane map: col=lane&15, row=(lane>>4)*4+r.
#pragma unroll
    for (int mi = 0; mi < 4; ++mi) {
#pragma unroll
        for (int ni = 0; ni < 4; ++ni) {
            const int m = mi * 16 + quad * 4;
            const int c = w * 64 + ni * 16 + row16;
#pragma unroll
            for (int r = 0; r < 4; ++r)
                cLds[m + r][c] = acc[mi][ni][r];
        }
    }
    __syncthreads();

    // Epilogue: wave w handles tokens w*16 .. w*16+15.
    for (int tt = 0; tt < 16; ++tt) {
        const int tok = w * 16 + tt;
        const int n   = n0 + tok;
        const int tid = token_ids[n];
        float sval = 0.0f;
        int eown = -1;
        if (l < TOPK) {
            eown = tid2eid[(size_t)tid * TOPK + l];
            const float logit = cLds[tok][eown];
            const float sp = fmaxf(logit, 0.0f) + log1pf(expf(-fabsf(logit)));
            sval = sqrtf(sp);
        }
        float sc[TOPK]; int eidx[TOPK];
        float denom = 0.0f;
#pragma unroll
        for (int k = 0; k < TOPK; ++k) {
            sc[k]   = __shfl(sval, k, 64);
            eidx[k] = __shfl(eown, k, 64);
            denom  += sc[k];
        }
        const float inv = RSCALE / fmaxf(denom, 1e-12f);
        float4 p, mv;
        float* pp = reinterpret_cast<float*>(&p);
        float* mm = reinterpret_cast<float*>(&mv);
#pragma unroll
        for (int c = 0; c < 4; ++c) {
            const int e = l * 4 + c;
            float pv = 0.0f, fv = 0.0f;
#pragma unroll
            for (int k = 0; k < TOPK; ++k)
                if (eidx[k] == e) { pv = sc[k] * inv; fv = 1.0f; }
            pp[c] = pv; mm[c] = fv;
        }
        reinterpret_cast<float4*>(out + (size_t)n * NEXP)[l] = p;
        reinterpret_cast<float4*>(out + (size_t)(M + n) * NEXP)[l] = mv;
    }
}

// Fallback (no workspace): fp32 gather, one wave per token.
__global__ __launch_bounds__(256) void router_fp32(
    const float* __restrict__ hidden, const int* __restrict__ token_ids,
    const float* __restrict__ weight, const int* __restrict__ tid2eid,
    float* __restrict__ out, int N) {
    const int lane = threadIdx.x & 63;
    const int n = blockIdx.x * 4 + (threadIdx.x >> 6);
    if (n >= N) return;
    const int tid = token_ids[n];
    const int* er = tid2eid + (size_t)tid * TOPK;
    int eidx[TOPK];
#pragma unroll
    for (int k = 0; k < TOPK; ++k) eidx[k] = er[k];
    const float4* h4 = reinterpret_cast<const float4*>(hidden + (size_t)n * DIM);
    float acc[TOPK] = {};
#pragma unroll
    for (int j = 0; j < 4; ++j) {
        const float4 a = h4[j * 128 + lane * 2];
        const float4 b = h4[j * 128 + lane * 2 + 1];
#pragma unroll
        for (int k = 0; k < TOPK; ++k) {
            const float4* wr = reinterpret_cast<const float4*>(weight + (size_t)eidx[k] * DIM);
            const float4 wa = wr[j * 128 + lane * 2];
            const float4 wb = wr[j * 128 + lane * 2 + 1];
            acc[k] += a.x * wa.x + a.y * wa.y + a.z * wa.z + a.w * wa.w
                    + b.x * wb.x + b.y * wb.y + b.z * wb.z + b.w * wb.w;
        }
    }
#pragma unroll
    for (int k = 0; k < TOPK; ++k) {
        float v = acc[k];
#pragma unroll
        for (int m = 1; m < 64; m <<= 1) v += __shfl_xor(v, m, 64);
        acc[k] = v;
    }
    float sval = 0.0f;
    if (lane < TOPK) {
        const float sp = fmaxf(acc[lane], 0.0f) + log1pf(expf(-fabsf(acc[lane])));
        sval = sqrtf(sp);
    }
    float sc[TOPK]; float denom = 0.0f;
#pragma unroll
    for (int k = 0; k < TOPK; ++k) { sc[k] = __shfl(sval, k, 64); denom += sc[k]; }
    const float inv = RSCALE / fmaxf(denom, 1e-12f);
    float4 p, mv;
    float* pp = reinterpret_cast<float*>(&p);
    float* mm = reinterpret_cast<float*>(&mv);
#pragma unroll
    for (int c = 0; c < 4; ++c) {
        const int e = lane * 4 + c;
        float pv = 0.0f, fv = 0.0f;
#pragma unroll
        for (int k = 0; k < TOPK; ++k)
            if (eidx[k] == e) { pv = sc[k] * inv; fv = 1.0f; }
        pp[c] = pv; mm[c] = fv;
    }
    reinterpret_cast<float4*>(out + (size_t)n * NEXP)[lane] = p;
    reinterpret_cast<float4*>(out + (size_t)(N + n) * NEXP)[lane] = mv;
}

extern "C" void kernel_launch(void* const* d_in, const int* in_sizes, int n_in,
                              void* d_out, int out_size, void* d_ws, size_t ws_size,
                              hipStream_t stream) {
    const float* hidden    = (const float*)d_in[0];
    const int*   token_ids = (const int*)d_in[1];   // int64 in ref -> int32 here
    const float* weight    = (const float*)d_in[2];
    const int*   tid2eid   = (const int*)d_in[3];
    float* out = (float*)d_out;
    const int M = in_sizes[1];  // B*S tokens

    const size_t need = (size_t)NEXP * DIM * sizeof(ushort);  // 1 MiB
    if (ws_size >= need && (M % BM) == 0) {
        unsigned int* wh = (unsigned int*)d_ws;
        const int n4 = NEXP * DIM / 4;
        convert_weight_f16<<<(n4 + 255) / 256, 256, 0, stream>>>(weight, wh, n4);
        router_mfma<<<M / BM, 256, 0, stream>>>(hidden, token_ids,
                                                (const ushort*)wh, tid2eid, out, M);
    } else {
        router_fp32<<<(M + 3) / 4, 256, 0, stream>>>(hidden, token_ids, weight,
                                                     tid2eid, out, M);
    }
}

// Round 8
// 58.279 us; speedup vs baseline: 1.5168x; 1.5168x over previous
//
#include <hip/hip_runtime.h>
#include <hip/hip_fp16.h>

// DeepseekV4HashRouter: B=4,S=4096,D=2048,E=256,K=8,V=128000
#define DIM    2048
#define NEXP   256
#define TOPK   8
#define RSCALE 2.5f
#define BM     32
#define BK     64
#define NT     (DIM / BK)   // 32 K-steps
#define NTHR   512          // 8 waves

typedef _Float16 h8 __attribute__((ext_vector_type(8)));
typedef float f32x4 __attribute__((ext_vector_type(4)));

__device__ __forceinline__ unsigned int pkh(float x, float y) {
    return __builtin_bit_cast(unsigned int, __builtin_amdgcn_cvt_pkrtz(x, y));
}

__global__ __launch_bounds__(256) void convert_weight_f16(
    const float* __restrict__ w, unsigned int* __restrict__ wh, int n4) {
    int i = blockIdx.x * blockDim.x + threadIdx.x;  // over float4s
    if (i < n4) {
        float4 f = reinterpret_cast<const float4*>(w)[i];
        uint2 o;
        o.x = pkh(f.x, f.y);
        o.y = pkh(f.z, f.w);
        reinterpret_cast<uint2*>(wh)[i] = o;
    }
}

// Dense MFMA router: block = 32 tokens x 256 experts, K = 2048.
// 8 waves; wave w owns 32 tokens x experts [w*32, w*32+32).
// Grid = M/32 = 512 blocks -> 2 blocks/CU (LDS 72KB), 4 waves/SIMD.
__global__ __launch_bounds__(NTHR) void router_mfma2(
    const float* __restrict__ hidden,   // [M, D] fp32
    const int* __restrict__ token_ids,  // [M] int32
    const ushort* __restrict__ wh,      // [E, D] f16
    const int* __restrict__ tid2eid,    // [V, K] int32
    float* __restrict__ out,            // probs [M,E] then map [M,E]
    int M) {
    __shared__ alignas(16) char smem[73728];   // A(2x4KB) + B(2x32KB); C reuses
    ushort* aLds = reinterpret_cast<ushort*>(smem);                 // [2][BM*BK]
    ushort* bLds = reinterpret_cast<ushort*>(smem + 2 * BM * BK * 2);  // [2][NEXP*BK]

    const int t  = threadIdx.x;
    const int w  = t >> 6;
    const int l  = t & 63;
    const int n0 = blockIdx.x * BM;

    // A staging: thread -> token row ar (16 thr/row), 4-f32 group aq.
    const int ar = t >> 4;
    const int aq = t & 15;
    const int s8 = aq >> 1, half = aq & 1;
    const int aslot = (s8 ^ (ar & 7)) * 8 + half * 4;  // ushort offset in row

    // B staging: wave w stages expert rows [w*32, w*32+32) in 4 issues of
    // 8 rows; linear LDS dest, XOR-involution applied on global source.
    auto stageB = [&](int kt, int s) {
#pragma unroll
        for (int i = 0; i < 4; ++i) {
            const int e0 = (w * 4 + i) * 8;
            const int e  = e0 + (l >> 3);
            const int gb = (l & 7) ^ (e & 7);
            const ushort* g = wh + (size_t)e * DIM + kt * BK + gb * 8;
            const ushort* lp = bLds + (size_t)s * (NEXP * BK) + e0 * BK;
            __builtin_amdgcn_global_load_lds(
                (const unsigned int __attribute__((address_space(1)))*)g,
                (unsigned int __attribute__((address_space(3)))*)lp, 16, 0, 0);
        }
    };
    auto writeA = [&](int s, float4 fa) {
        uint2 u;
        u.x = pkh(fa.x, fa.y);
        u.y = pkh(fa.z, fa.w);
        *reinterpret_cast<uint2*>(aLds + (size_t)s * (BM * BK) + ar * BK + aslot) = u;
    };

    // Prologue: stage kt=0 into buffer 0.
    {
        const float4 fa = *reinterpret_cast<const float4*>(
            hidden + (size_t)(n0 + ar) * DIM + aq * 4);
        stageB(0, 0);
        writeA(0, fa);
    }
    __syncthreads();

    f32x4 acc[2][2] = {};
    const int row16 = l & 15;
    const int quad  = l >> 4;

    for (int kt = 0; kt < NT; ++kt) {
        const int cur = kt & 1;
        const bool more = (kt + 1) < NT;
        float4 fa;
        if (more) {  // issue next-tile loads before compute
            fa = *reinterpret_cast<const float4*>(
                hidden + (size_t)(n0 + ar) * DIM + (kt + 1) * BK + aq * 4);
            stageB(kt + 1, cur ^ 1);
        }
        const ushort* aB = aLds + (size_t)cur * (BM * BK);
        const ushort* bB = bLds + (size_t)cur * (NEXP * BK);
#pragma unroll
        for (int kk = 0; kk < 2; ++kk) {
            const int bb = kk * 4 + quad;
            h8 af[2], bf[2];
#pragma unroll
            for (int mi = 0; mi < 2; ++mi) {
                const int r = mi * 16 + row16;
                af[mi] = *reinterpret_cast<const h8*>(aB + r * BK + (bb ^ (r & 7)) * 8);
            }
#pragma unroll
            for (int ni = 0; ni < 2; ++ni) {
                const int c = w * 32 + ni * 16 + row16;
                bf[ni] = *reinterpret_cast<const h8*>(bB + c * BK + (bb ^ (c & 7)) * 8);
            }
#pragma unroll
            for (int mi = 0; mi < 2; ++mi)
#pragma unroll
                for (int ni = 0; ni < 2; ++ni)
                    acc[mi][ni] = __builtin_amdgcn_mfma_f32_16x16x32_f16(
                        af[mi], bf[ni], acc[mi][ni], 0, 0, 0);
        }
        if (more) writeA(cur ^ 1, fa);
        __syncthreads();
    }

    // Scatter logits into C-LDS (reuses A/B region; all reads done at barrier).
    float (*cLds)[NEXP + 1] = reinterpret_cast<float (*)[NEXP + 1]>(smem);
#pragma unroll
    for (int mi = 0; mi < 2; ++mi) {
#pragma unroll
        for (int ni = 0; ni < 2; ++ni) {
            const int m = mi * 16 + quad * 4;
            const int c = w * 32 + ni * 16 + row16;
#pragma unroll
            for (int r = 0; r < 4; ++r)
                cLds[m + r][c] = acc[mi][ni][r];
        }
    }
    __syncthreads();

    // Epilogue: wave w handles tokens w*4 .. w*4+3.
#pragma unroll
    for (int tt = 0; tt < 4; ++tt) {
        const int tok = w * 4 + tt;
        const int n   = n0 + tok;
        const int tid = token_ids[n];
        float sval = 0.0f;
        int eown = -1;
        if (l < TOPK) {
            eown = tid2eid[(size_t)tid * TOPK + l];
            const float logit = cLds[tok][eown];
            const float sp = fmaxf(logit, 0.0f) + log1pf(expf(-fabsf(logit)));
            sval = sqrtf(sp);
        }
        float sc[TOPK]; int eidx[TOPK];
        float denom = 0.0f;
#pragma unroll
        for (int k = 0; k < TOPK; ++k) {
            sc[k]   = __shfl(sval, k, 64);
            eidx[k] = __shfl(eown, k, 64);
            denom  += sc[k];
        }
        const float inv = RSCALE / fmaxf(denom, 1e-12f);
        float4 p, mv;
        float* pp = reinterpret_cast<float*>(&p);
        float* mm = reinterpret_cast<float*>(&mv);
#pragma unroll
        for (int c = 0; c < 4; ++c) {
            const int e = l * 4 + c;
            float pv = 0.0f, fv = 0.0f;
#pragma unroll
            for (int k = 0; k < TOPK; ++k)
                if (eidx[k] == e) { pv = sc[k] * inv; fv = 1.0f; }
            pp[c] = pv; mm[c] = fv;
        }
        reinterpret_cast<float4*>(out + (size_t)n * NEXP)[l] = p;
        reinterpret_cast<float4*>(out + (size_t)(M + n) * NEXP)[l] = mv;
    }
}

// Fallback (no workspace): fp32 gather, one wave per token.
__global__ __launch_bounds__(256) void router_fp32(
    const float* __restrict__ hidden, const int* __restrict__ token_ids,
    const float* __restrict__ weight, const int* __restrict__ tid2eid,
    float* __restrict__ out, int N) {
    const int lane = threadIdx.x & 63;
    const int n = blockIdx.x * 4 + (threadIdx.x >> 6);
    if (n >= N) return;
    const int tid = token_ids[n];
    const int* er = tid2eid + (size_t)tid * TOPK;
    int eidx[TOPK];
#pragma unroll
    for (int k = 0; k < TOPK; ++k) eidx[k] = er[k];
    const float4* h4 = reinterpret_cast<const float4*>(hidden + (size_t)n * DIM);
    float acc[TOPK] = {};
#pragma unroll
    for (int j = 0; j < 4; ++j) {
        const float4 a = h4[j * 128 + lane * 2];
        const float4 b = h4[j * 128 + lane * 2 + 1];
#pragma unroll
        for (int k = 0; k < TOPK; ++k) {
            const float4* wr = reinterpret_cast<const float4*>(weight + (size_t)eidx[k] * DIM);
            const float4 wa = wr[j * 128 + lane * 2];
            const float4 wb = wr[j * 128 + lane * 2 + 1];
            acc[k] += a.x * wa.x + a.y * wa.y + a.z * wa.z + a.w * wa.w
                    + b.x * wb.x + b.y * wb.y + b.z * wb.z + b.w * wb.w;
        }
    }
#pragma unroll
    for (int k = 0; k < TOPK; ++k) {
        float v = acc[k];
#pragma unroll
        for (int m = 1; m < 64; m <<= 1) v += __shfl_xor(v, m, 64);
        acc[k] = v;
    }
    float sval = 0.0f;
    if (lane < TOPK) {
        const float sp = fmaxf(acc[lane], 0.0f) + log1pf(expf(-fabsf(acc[lane])));
        sval = sqrtf(sp);
    }
    float sc[TOPK]; float denom = 0.0f;
#pragma unroll
    for (int k = 0; k < TOPK; ++k) { sc[k] = __shfl(sval, k, 64); denom += sc[k]; }
    const float inv = RSCALE / fmaxf(denom, 1e-12f);
    float4 p, mv;
    float* pp = reinterpret_cast<float*>(&p);
    float* mm = reinterpret_cast<float*>(&mv);
#pragma unroll
    for (int c = 0; c < 4; ++c) {
        const int e = lane * 4 + c;
        float pv = 0.0f, fv = 0.0f;
#pragma unroll
        for (int k = 0; k < TOPK; ++k)
            if (eidx[k] == e) { pv = sc[k] * inv; fv = 1.0f; }
        pp[c] = pv; mm[c] = fv;
    }
    reinterpret_cast<float4*>(out + (size_t)n * NEXP)[lane] = p;
    reinterpret_cast<float4*>(out + (size_t)(N + n) * NEXP)[lane] = mv;
}

extern "C" void kernel_launch(void* const* d_in, const int* in_sizes, int n_in,
                              void* d_out, int out_size, void* d_ws, size_t ws_size,
                              hipStream_t stream) {
    const float* hidden    = (const float*)d_in[0];
    const int*   token_ids = (const int*)d_in[1];   // int64 in ref -> int32 here
    const float* weight    = (const float*)d_in[2];
    const int*   tid2eid   = (const int*)d_in[3];
    float* out = (float*)d_out;
    const int M = in_sizes[1];  // B*S tokens

    const size_t need = (size_t)NEXP * DIM * sizeof(ushort);  // 1 MiB
    if (ws_size >= need && (M % BM) == 0) {
        unsigned int* wh = (unsigned int*)d_ws;
        const int n4 = NEXP * DIM / 4;
        convert_weight_f16<<<(n4 + 255) / 256, 256, 0, stream>>>(weight, wh, n4);
        router_mfma2<<<M / BM, NTHR, 0, stream>>>(hidden, token_ids,
                                                  (const ushort*)wh, tid2eid, out, M);
    } else {
        router_fp32<<<(M + 3) / 4, 256, 0, stream>>>(hidden, token_ids, weight,
                                                     tid2eid, out, M);
    }
}